// Round 17
// baseline (560.851 us; speedup 1.0000x reference)
//
#include <hip/hip_runtime.h>

typedef unsigned short u16;
typedef __attribute__((ext_vector_type(8))) short bh8;
typedef __attribute__((ext_vector_type(4))) float f4;

__device__ __forceinline__ u16 f2b(float f){
  unsigned int u = __float_as_uint(f);
  u += 0x7fffu + ((u >> 16) & 1u);
  return (u16)(u >> 16);
}
__device__ __forceinline__ float b2f(u16 h){
  return __uint_as_float(((unsigned int)h) << 16);
}
__device__ __forceinline__ void gl16(const u16* g, u16* l){
  __builtin_amdgcn_global_load_lds((const __attribute__((address_space(1))) void*)g,
                                   (__attribute__((address_space(3))) void*)l, 16, 0, 0);
}

// ---------------- merged packing ----------------
// y = 0..5 : plain bf16 cast of six 512K-element weights
// y = 6    : ce3 (262144)
// y = 7    : dw tap-major (4608) + slack zero (2048)
// y = 8,9  : c_kv pair (600,300) -> padded [640][320]
__global__ void pack_all(const float* __restrict__ s0, const float* __restrict__ s1,
                         const float* __restrict__ s2, const float* __restrict__ s3,
                         const float* __restrict__ s4, const float* __restrict__ s5,
                         const float* __restrict__ sce3, const float* __restrict__ sdw,
                         const float* __restrict__ sckvA, const float* __restrict__ sckvB,
                         u16* __restrict__ d0, u16* __restrict__ d1,
                         u16* __restrict__ d2, u16* __restrict__ d3,
                         u16* __restrict__ d45, u16* __restrict__ dce3,
                         u16* __restrict__ ddw, u16* __restrict__ slack,
                         u16* __restrict__ dckvA, u16* __restrict__ dckvB)
{
  const int i = blockIdx.x*256 + threadIdx.x;
  const int y = blockIdx.y;
  if (y < 6){
    const float* src = (y==0)?s0:(y==1)?s1:(y==2)?s2:(y==3)?s3:(y==4)?s4:s5;
    u16* dst = (y==0)?d0:(y==1)?d1:(y==2)?d2:(y==3)?d3:(y==4)?d45:(d45+524288);
    dst[i] = f2b(src[i]);
  } else if (y == 6){
    if (i < 262144) dce3[i] = f2b(sce3[i]);
  } else if (y == 7){
    if (i < 4608){
      int t = i >> 9, c = i & 511;
      ddw[i] = f2b(sdw[c*9 + t]);
    } else if (i < 4608 + 2048){
      slack[i - 4608] = 0;
    }
  } else {
    if (i < 204800){   // 640*320
      const float* src = (y == 9) ? sckvB : sckvA;
      u16* dst = (y == 9) ? dckvB : dckvA;
      int nn = i / 320, kk = i - (i/320)*320;
      int t_ = (nn >= 320) ? 1 : 0;
      int rem = nn - t_*320;
      int hh = rem / 80, dd = rem - hh*80;
      int kh = kk / 80, kd = kk - kh*80;
      float v = 0.f;
      if (dd < 75 && kd < 75)
        v = src[(size_t)(t_*300 + hh*75 + dd)*300 + (kh*75 + kd)];
      dst[i] = f2b(v);
    }
  }
}

// ---------------- x (B,C,H,W) f32 -> t (B,N,C) bf16; z>=64 -> second input ----------------
__global__ __launch_bounds__(256)
void transpose_k(const float* __restrict__ xa, const float* __restrict__ xb, u16* __restrict__ t)
{
  __shared__ float tile[32][33];
  const int n0 = blockIdx.x * 32, c0 = blockIdx.y * 32;
  const int z = blockIdx.z;
  const int b = z & 63;
  const float* x = (z >= 64) ? xb : xa;
  u16* to = t + (size_t)(z >= 64 ? 19200*512 : 0);
  const int ln = threadIdx.x & 31, lr = threadIdx.x >> 5;
  #pragma unroll
  for (int q = 0; q < 4; q++) {
    const int c = c0 + lr + q*8, n = n0 + ln;
    tile[lr + q*8][ln] = (n < 300) ? x[((long)b*512 + c)*300 + n] : 0.f;
  }
  __syncthreads();
  #pragma unroll
  for (int q = 0; q < 4; q++) {
    const int n = n0 + lr + q*8;
    if (n < 300) to[((long)b*300 + n)*512 + c0 + ln] = f2b(tile[ln][lr + q*8]);
  }
}

// ---------------- 256x256 MFMA GEMM, BK=32, 2-buffer depth-2 counted pipeline ----------------
// Round-10 schedule (correctness HW-verified) with the VGPR clamp REMOVED (no min-waves arg).
// 8 waves (512 thr), per-wave 128x64 (8x4 frags). LDS 64KB.
// Per K-step t: compute(buf[t&1]) -> barrier -> issue S_{t+2} into buf[t&1]
//   -> vmcnt(4) (drains S_{t+1}; S_{t+2} stays in flight ~1 iter) -> barrier.
// XOR swizzle chunk^((row>>1)&3), both sides. Bijective XCD remap. Paired weights via mhalf.
// OUTF: 0 = bf16 out (+bias if HASB); 2 = split: n<512 -> bf16 via (u16*)Cf, n>=512 -> bf16+bias.
template<int OUTF, int HASB>
__global__ __launch_bounds__(512)
void gemm2(const u16* __restrict__ A, int lda,
           const u16* __restrict__ Bw, const u16* __restrict__ Bw2, int ldb, long mhalf,
           u16* __restrict__ Cb, float* __restrict__ Cf, int ldc,
           const float* __restrict__ bias, const float* __restrict__ bias2, int K)
{
  __shared__ u16 As[2][8192];   // 256 x 32 per buf
  __shared__ u16 Bs[2][8192];
  const int tid = threadIdx.x;
  const int gx = gridDim.x;
  const int nwg = gx * gridDim.y;
  const int flat = blockIdx.y * gx + blockIdx.x;
  const int qq = nwg >> 3, rr = nwg & 7, xcd = flat & 7, lin = flat >> 3;
  const int newid = (xcd < rr ? xcd*(qq+1) : rr*(qq+1) + (xcd-rr)*qq) + lin;
  const long n0 = (long)(newid % gx) * 256;
  const long m0 = (long)(newid / gx) * 256;
  const u16* Bwp = Bw; const float* bp = bias;
  if (Bw2 != nullptr && m0 >= mhalf){ Bwp = Bw2; bp = bias2; }
  const int wave = tid >> 6, lane = tid & 63;
  const int l15 = lane & 15, lg = lane >> 4;
  const int wr = (wave >> 2) * 128;   // 2 M-groups
  const int wc = (wave & 3) * 64;     // 4 N-groups
  const int srow = tid >> 2;
  const int gseg = ((tid & 3) ^ ((tid >> 3) & 3)) * 8;
  const u16* Ag0 = A   + (m0 + srow)       * (long)lda + gseg;
  const u16* Ag1 = A   + (m0 + 128 + srow) * (long)lda + gseg;
  const u16* Bg0 = Bwp + (n0 + srow)       * (long)ldb + gseg;
  const u16* Bg1 = Bwp + (n0 + 128 + srow) * (long)ldb + gseg;
  const int to8 = tid * 8;
  int roA[8], roB[4];
  #pragma unroll
  for (int i = 0; i < 8; i++){ const int rA = wr + i*16 + l15; roA[i] = rA*32 + ((lg ^ ((rA >> 1) & 3)) * 8); }
  #pragma unroll
  for (int i = 0; i < 4; i++){ const int rB = wc + i*16 + l15; roB[i] = rB*32 + ((lg ^ ((rB >> 1) & 3)) * 8); }
  f4 acc[8][4] = {};
  const int NT = K >> 5;
  // prologue: S0 -> buf0, S1 -> buf1 (8 loads); wait 4 => S0 landed
  gl16(Ag0,      &As[0][to8]); gl16(Ag1,      &As[0][4096 + to8]);
  gl16(Bg0,      &Bs[0][to8]); gl16(Bg1,      &Bs[0][4096 + to8]);
  gl16(Ag0 + 32, &As[1][to8]); gl16(Ag1 + 32, &As[1][4096 + to8]);
  gl16(Bg0 + 32, &Bs[1][to8]); gl16(Bg1 + 32, &Bs[1][4096 + to8]);
  asm volatile("s_waitcnt vmcnt(4)" ::: "memory");
  __builtin_amdgcn_sched_barrier(0);
  __builtin_amdgcn_s_barrier();
  __builtin_amdgcn_sched_barrier(0);
  for (int t = 0; t < NT; t++) {
    const int cur = t & 1;
    bh8 af[8], bf[4];
    #pragma unroll
    for (int mi = 0; mi < 8; mi++) af[mi] = *(const bh8*)&As[cur][roA[mi]];
    #pragma unroll
    for (int ni = 0; ni < 4; ni++) bf[ni] = *(const bh8*)&Bs[cur][roB[ni]];
    __builtin_amdgcn_s_setprio(1);
    #pragma unroll
    for (int mi = 0; mi < 8; mi++)
      #pragma unroll
      for (int ni = 0; ni < 4; ni++)
        acc[mi][ni] = __builtin_amdgcn_mfma_f32_16x16x32_bf16(af[mi], bf[ni], acc[mi][ni], 0, 0, 0);
    __builtin_amdgcn_s_setprio(0);
    if (t + 1 < NT) {
      __builtin_amdgcn_sched_barrier(0);
      __builtin_amdgcn_s_barrier();        // all waves done reading buf[cur]
      __builtin_amdgcn_sched_barrier(0);
      if (t + 2 < NT) {
        const int kt = (t + 2) << 5;
        gl16(Ag0 + kt, &As[cur][to8]); gl16(Ag1 + kt, &As[cur][4096 + to8]);
        gl16(Bg0 + kt, &Bs[cur][to8]); gl16(Bg1 + kt, &Bs[cur][4096 + to8]);
        asm volatile("s_waitcnt vmcnt(4)" ::: "memory");   // S_{t+1} landed
      } else {
        asm volatile("s_waitcnt vmcnt(0)" ::: "memory");   // last stage
      }
      __builtin_amdgcn_sched_barrier(0);
      __builtin_amdgcn_s_barrier();        // publish S_{t+1} to all waves
      __builtin_amdgcn_sched_barrier(0);
    }
  }
  if (OUTF == 2) {
    u16* resb16 = (u16*)Cf;
    if (n0 < 512) {
      #pragma unroll
      for (int ni = 0; ni < 4; ni++) {
        const long cn = n0 + wc + ni*16 + l15;
        #pragma unroll
        for (int mi = 0; mi < 8; mi++)
          #pragma unroll
          for (int r = 0; r < 4; r++) {
            const long cm = m0 + wr + mi*16 + lg*4 + r;
            resb16[cm * ldc + cn] = f2b(acc[mi][ni][r]);
          }
      }
    } else {
      #pragma unroll
      for (int ni = 0; ni < 4; ni++) {
        const long cn = n0 - 512 + wc + ni*16 + l15;
        const float bv = bias[cn];
        #pragma unroll
        for (int mi = 0; mi < 8; mi++)
          #pragma unroll
          for (int r = 0; r < 4; r++) {
            const long cm = m0 + wr + mi*16 + lg*4 + r;
            Cb[cm * ldc + cn] = f2b(acc[mi][ni][r] + bv);
          }
      }
    }
  } else {
    #pragma unroll
    for (int ni = 0; ni < 4; ni++) {
      const long cn = n0 + wc + ni*16 + l15;
      const float bv = HASB ? bp[cn] : 0.0f;
      #pragma unroll
      for (int mi = 0; mi < 8; mi++)
        #pragma unroll
        for (int r = 0; r < 4; r++) {
          const long cm = m0 + wr + mi*16 + lg*4 + r;
          Cb[cm * ldc + cn] = f2b(acc[mi][ni][r] + bv);
        }
    }
  }
}

// ---------------- 256x128 MFMA GEMM (3-stage counted vmcnt) — used for ckv (N=640) ----------------
template<int OUTF, int HASB>
__global__ __launch_bounds__(512)
void gemm_k(const u16* __restrict__ A, int lda,
            const u16* __restrict__ Bw, const u16* __restrict__ Bw2, int ldb, long mhalf,
            u16* __restrict__ Cb, float* __restrict__ Cf, int ldc,
            const float* __restrict__ bias, const float* __restrict__ bias2, int K)
{
  __shared__ u16 As[3][8192];
  __shared__ u16 Bs[3][4096];
  const int tid = threadIdx.x;
  const int gx = gridDim.x;
  const int nwg = gx * gridDim.y;
  const int flat = blockIdx.y * gx + blockIdx.x;
  const int qq = nwg >> 3, rr = nwg & 7, xcd = flat & 7, lin = flat >> 3;
  const int newid = (xcd < rr ? xcd*(qq+1) : rr*(qq+1) + (xcd-rr)*qq) + lin;
  const long n0 = (long)(newid % gx) * 128;
  const long m0 = (long)(newid / gx) * 256;
  const u16* Bwp = Bw; const float* bp = bias;
  if (Bw2 != nullptr && m0 >= mhalf){ Bwp = Bw2; bp = bias2; }
  const int wave = tid >> 6, lane = tid & 63;
  const int l15 = lane & 15, lg = lane >> 4;
  const int wr = (wave >> 1) * 64, wc = (wave & 1) * 64;
  const int arow = tid >> 2;
  const int aseg = ((tid & 3) ^ ((arow >> 1) & 3)) * 8;
  const u16* Ag0 = A + (m0 + arow) * (long)lda + aseg;
  const u16* Ag1 = A + (m0 + 128 + arow) * (long)lda + aseg;
  const u16* Bg0 = Bwp + (n0 + arow) * (long)ldb + aseg;
  const int to8 = tid * 8;
  int roA[4], roB[4];
  #pragma unroll
  for (int i = 0; i < 4; i++){
    const int rA = wr + i*16 + l15;
    roA[i] = rA*32 + ((lg ^ ((rA >> 1) & 3)) * 8);
    const int rB = wc + i*16 + l15;
    roB[i] = rB*32 + ((lg ^ ((rB >> 1) & 3)) * 8);
  }
  f4 acc[4][4] = {};
  const int NT = K >> 5;
  {
    gl16(Ag0, &As[0][to8]); gl16(Ag1, &As[0][4096 + to8]); gl16(Bg0, &Bs[0][to8]);
    gl16(Ag0 + 32, &As[1][to8]); gl16(Ag1 + 32, &As[1][4096 + to8]); gl16(Bg0 + 32, &Bs[1][to8]);
  }
  int rd = 0;
  for (int t = 0; t < NT; t++) {
    if (t < NT - 1) { asm volatile("s_waitcnt vmcnt(3)" ::: "memory"); }
    else            { asm volatile("s_waitcnt vmcnt(0)" ::: "memory"); }
    __builtin_amdgcn_sched_barrier(0);
    __builtin_amdgcn_s_barrier();
    __builtin_amdgcn_sched_barrier(0);
    if (t + 2 < NT) {
      int wb = rd + 2; if (wb >= 3) wb -= 3;
      const int kt = (t + 2) << 5;
      gl16(Ag0 + kt, &As[wb][to8]); gl16(Ag1 + kt, &As[wb][4096 + to8]); gl16(Bg0 + kt, &Bs[wb][to8]);
    }
    bh8 af[4], bf[4];
    #pragma unroll
    for (int mi = 0; mi < 4; mi++) af[mi] = *(const bh8*)&As[rd][roA[mi]];
    #pragma unroll
    for (int ni = 0; ni < 4; ni++) bf[ni] = *(const bh8*)&Bs[rd][roB[ni]];
    __builtin_amdgcn_s_setprio(1);
    #pragma unroll
    for (int mi = 0; mi < 4; mi++)
      #pragma unroll
      for (int ni = 0; ni < 4; ni++)
        acc[mi][ni] = __builtin_amdgcn_mfma_f32_16x16x32_bf16(af[mi], bf[ni], acc[mi][ni], 0, 0, 0);
    __builtin_amdgcn_s_setprio(0);
    rd++; if (rd == 3) rd = 0;
  }
  #pragma unroll
  for (int ni = 0; ni < 4; ni++) {
    const long cn = n0 + wc + ni*16 + l15;
    const float bv = HASB ? bp[cn] : 0.0f;
    #pragma unroll
    for (int mi = 0; mi < 4; mi++) {
      #pragma unroll
      for (int r = 0; r < 4; r++) {
        const long cm = m0 + wr + mi*16 + lg*4 + r;
        Cb[cm * ldc + cn] = f2b(acc[mi][ni][r] + bv);
      }
    }
  }
}

// ---------------- LayerNorm(1024) + relu; split into s and cT; z selects stream ----------------
__global__ __launch_bounds__(256)
void ln_kernel(const u16* __restrict__ apre,
               const float* __restrict__ lw1, const float* __restrict__ lb1,
               const float* __restrict__ lw2, const float* __restrict__ lb2,
               u16* __restrict__ s, u16* __restrict__ cT)
{
  __shared__ u16 tile[40][520];
  const int bh = blockIdx.x;
  const int b = bh >> 2, h = bh & 3;
  const int z = blockIdx.y;
  const int p = blockIdx.z;
  const float* lw = p ? lw2 : lw1;
  const float* lb = p ? lb2 : lb1;
  const u16* ap = apre + (size_t)p * 19200 * 1024;
  u16* sp = s + (size_t)p * 19200 * 512;
  u16* cp = cT + (size_t)p * 64 * 512 * 320;
  const int dd0 = z ? 40 : 0;
  const int ndd = z ? 35 : 40;
  const int segbase = z ? 5 : 0;
  const int tid = threadIdx.x, w = tid >> 6, lane = tid & 63;
  const int r0 = b*300 + h*75 + dd0;
  for (int dl = w; dl < ndd; dl += 4){
    const int r = r0 + dl;
    const u16* row = ap + (size_t)r*1024 + lane*8;
    const bh8 vc = *(const bh8*)row;
    const bh8 vs = *(const bh8*)(row + 512);
    float fc[8], fs[8];
    float sm = 0.f, sq = 0.f;
    #pragma unroll
    for (int j = 0; j < 8; j++){
      fc[j] = b2f((u16)vc[j]); fs[j] = b2f((u16)vs[j]);
      sm += fc[j] + fs[j];
      sq += fc[j]*fc[j] + fs[j]*fs[j];
    }
    #pragma unroll
    for (int o = 32; o; o >>= 1){ sm += __shfl_xor(sm, o); sq += __shfl_xor(sq, o); }
    const float mean = sm * (1.f/1024.f);
    const float rstd = rsqrtf(sq*(1.f/1024.f) - mean*mean + 1e-5f);
    bh8 oc, os;
    #pragma unroll
    for (int j = 0; j < 8; j++){
      const int c = lane*8 + j;
      const float y1 = (fc[j]-mean)*rstd*lw[c] + lb[c];
      oc[j] = (short)f2b(fmaxf(y1, 0.f));
      const float y2 = (fs[j]-mean)*rstd*lw[512+c] + lb[512+c];
      os[j] = (short)f2b(fmaxf(y2, 0.f));
    }
    *(bh8*)&tile[dl][lane*8] = oc;
    *(bh8*)&sp[(size_t)r*512 + lane*8] = os;
  }
  __syncthreads();
  for (int i = tid; i < 2560; i += 256){
    const int c = i / 5, sg = i - (i/5)*5;
    const int seg = segbase + sg;
    bh8 ov;
    #pragma unroll
    for (int j = 0; j < 8; j++){
      const int dl = seg*8 + j - dd0;
      ov[j] = (short)((dl >= 0 && dl < ndd) ? tile[dl][c] : (u16)0);
    }
    *(bh8*)&cp[((size_t)b*512 + c)*320 + h*80 + seg*8] = ov;
  }
}

// ---------------- attn ctx ----------------
template<int D, int DREAL, int OS>
__global__ __launch_bounds__(256)
void ctx_kernel(const u16* __restrict__ kva, const u16* __restrict__ kvb,
                u16* __restrict__ outp, int K, int RS, int VOFF, float scale)
{
  constexpr int NT = D/16, MT = D/16, MTL = (MT+3)/4, SEG = D/8;
  __shared__ u16 vT[D][40];
  __shared__ u16 kT[D][40];
  const int h = blockIdx.x, b = blockIdx.y, iq = blockIdx.z;
  const int Hn = gridDim.x;
  const u16* base = (iq ? kvb : kva) + (size_t)b*K*RS + h*D;
  u16* out = outp + (((size_t)iq*64 + b)*Hn + h)*(size_t)(D*OS);
  const int tid = threadIdx.x, w = tid >> 6, lane = tid & 63, l15 = lane & 15, lg = lane >> 4;
  f4 acc[MTL][NT] = {};
  for (int k0 = 0; k0 < K; k0 += 32) {
    __syncthreads();
    for (int sI = tid; sI < 32*SEG; sI += 256) {
      const int nn = sI / SEG, dseg = sI - (sI/SEG)*SEG;
      bh8 kk = {}, vv = {};
      const int krow = k0 + nn;
      if (krow < K) {
        const u16* p = base + (size_t)krow*RS + dseg*8;
        kk = *(const bh8*)p;
        vv = *(const bh8*)(p + VOFF);
      }
      #pragma unroll
      for (int j = 0; j < 8; j++){
        kT[dseg*8+j][nn] = (u16)kk[j];
        vT[dseg*8+j][nn] = (u16)vv[j];
      }
    }
    __syncthreads();
    #pragma unroll
    for (int ii = 0; ii < MTL; ii++){
      const int mt = w + ii*4;
      if (MT % 4 != 0 && mt >= MT) break;
      const bh8 a = *(const bh8*)&vT[mt*16 + l15][lg*8];
      #pragma unroll
      for (int nt = 0; nt < NT; nt++){
        const bh8 bb = *(const bh8*)&kT[nt*16 + l15][lg*8];
        acc[ii][nt] = __builtin_amdgcn_mfma_f32_16x16x32_bf16(a, bb, acc[ii][nt], 0, 0, 0);
      }
    }
  }
  #pragma unroll
  for (int ii = 0; ii < MTL; ii++){
    const int mt = w + ii*4;
    if (MT % 4 != 0 && mt >= MT) continue;
    #pragma unroll
    for (int r = 0; r < 4; r++){
      const int e = mt*16 + lg*4 + r;
      float xs[NT]; float mx = -1e30f;
      #pragma unroll
      for (int nt = 0; nt < NT; nt++){
        float x = acc[ii][nt][r] * scale;
        if (DREAL != D && (nt*16 + l15) >= DREAL) x = -1e30f;
        xs[nt] = x; mx = fmaxf(mx, x);
      }
      mx = fmaxf(mx, __shfl_xor(mx,1)); mx = fmaxf(mx, __shfl_xor(mx,2));
      mx = fmaxf(mx, __shfl_xor(mx,4)); mx = fmaxf(mx, __shfl_xor(mx,8));
      float smv = 0.f;
      #pragma unroll
      for (int nt = 0; nt < NT; nt++){
        const float p = (xs[nt] > -1e29f) ? __expf(xs[nt]-mx) : 0.f;
        xs[nt] = p; smv += p;
      }
      smv += __shfl_xor(smv,1); smv += __shfl_xor(smv,2);
      smv += __shfl_xor(smv,4); smv += __shfl_xor(smv,8);
      const float inv = 1.f / smv;
      #pragma unroll
      for (int nt = 0; nt < NT; nt++)
        out[(size_t)e*OS + nt*16 + l15] = f2b(xs[nt]*inv);
      if (OS > D) out[(size_t)e*OS + D + l15] = 0;
    }
  }
}

// ---------------- merged spatial + channel out: z=0 -> spatial, z=1,2 -> channel ----------------
__global__ __launch_bounds__(256)
void spch_out_kernel(const u16* __restrict__ s1, const u16* __restrict__ s2,
                     const u16* __restrict__ csT,
                     const u16* __restrict__ cT1, const u16* __restrict__ cT2,
                     const u16* __restrict__ ccT, u16* __restrict__ merge)
{
  const int tid = threadIdx.x, w = tid >> 6, lane = tid & 63, l15 = lane & 15, lg = lane >> 4;
  const int b = blockIdx.y;
  if (blockIdx.z == 0) {
    const int h = blockIdx.x;
    const u16* c1 = csT + (((size_t)b)*8 + h)*4096;
    const u16* c2 = csT + (((size_t)64 + b)*8 + h)*4096;
    for (int mt = w; mt < 19; mt += 4) {
      const int m = mt*16 + l15;
      const bool mv = (m < 300);
      const u16* q1 = s1 + ((size_t)b*300 + m)*512 + h*64;
      const u16* q2 = s2 + ((size_t)b*300 + m)*512 + h*64;
      f4 acc[4] = {};
      #pragma unroll
      for (int kc = 0; kc < 2; kc++){
        bh8 a1 = {}, a2 = {};
        if (mv){ a1 = *(const bh8*)(q1 + kc*32 + lg*8); a2 = *(const bh8*)(q2 + kc*32 + lg*8); }
        #pragma unroll
        for (int nt = 0; nt < 4; nt++){
          const bh8 b2v = *(const bh8*)&c2[(size_t)(nt*16+l15)*64 + kc*32 + lg*8];
          acc[nt] = __builtin_amdgcn_mfma_f32_16x16x32_bf16(a1, b2v, acc[nt], 0, 0, 0);
          const bh8 b1v = *(const bh8*)&c1[(size_t)(nt*16+l15)*64 + kc*32 + lg*8];
          acc[nt] = __builtin_amdgcn_mfma_f32_16x16x32_bf16(a2, b1v, acc[nt], 0, 0, 0);
        }
      }
      #pragma unroll
      for (int nt = 0; nt < 4; nt++)
        #pragma unroll
        for (int r = 0; r < 4; r++){
          const int mm = mt*16 + lg*4 + r;
          if (mm < 300)
            merge[((size_t)b*300 + mm)*1024 + h*64 + nt*16 + l15] = f2b(acc[nt][r]);
        }
    }
  } else {
    const int idx = (blockIdx.z - 1)*8 + blockIdx.x;  // 0..15
    const int cb = idx >> 2, h = idx & 3;
    const int chbase = cb*128 + w*32;
    f4 acc[5][2] = {};
    #pragma unroll
    for (int oi = 0; oi < 2; oi++){
      const u16* Am = ccT + (((size_t)((oi==0)?1:0)*64 + b)*4 + h)*(size_t)(80*96);
      const u16* qb = (oi==0) ? cT1 : cT2;
      #pragma unroll
      for (int kc = 0; kc < 3; kc++){
        bh8 bf[2];
        #pragma unroll
        for (int nf = 0; nf < 2; nf++){
          const int ch = chbase + nf*16 + l15;
          bf[nf] = *(const bh8*)&qb[((size_t)b*512 + ch)*320 + h*80 + kc*32 + lg*8];
        }
        #pragma unroll
        for (int mt = 0; mt < 5; mt++){
          const bh8 a = *(const bh8*)&Am[(size_t)(mt*16+l15)*96 + kc*32 + lg*8];
          #pragma unroll
          for (int nf = 0; nf < 2; nf++)
            acc[mt][nf] = __builtin_amdgcn_mfma_f32_16x16x32_bf16(a, bf[nf], acc[mt][nf], 0, 0, 0);
        }
      }
    }
    #pragma unroll
    for (int mt = 0; mt < 5; mt++)
      #pragma unroll
      for (int nf = 0; nf < 2; nf++)
        #pragma unroll
        for (int r = 0; r < 4; r++){
          const int e = mt*16 + lg*4 + r;
          if (e < 75)
            merge[((size_t)b*300 + h*75 + e)*1024 + 512 + chbase + nf*16 + l15] = f2b(acc[mt][nf][r]);
        }
  }
}

// ---------------- depthwise 3x3 + bias + leaky(0.01) ----------------
__global__ __launch_bounds__(256)
void dw_kernel(const u16* __restrict__ e1, const u16* __restrict__ dwt,
               const float* __restrict__ bias, u16* __restrict__ d1)
{
  const int idx = blockIdx.x*256 + threadIdx.x;
  const int cg = idx & 63;
  const int sp = (idx >> 6) % 300;
  const int b  = idx / (64*300);
  const int c0 = cg*8;
  const int hh = sp / 15, ww = sp - hh*15;
  float acc[8];
  {
    const float4 b0 = *(const float4*)&bias[c0];
    const float4 b1 = *(const float4*)&bias[c0+4];
    acc[0]=b0.x; acc[1]=b0.y; acc[2]=b0.z; acc[3]=b0.w;
    acc[4]=b1.x; acc[5]=b1.y; acc[6]=b1.z; acc[7]=b1.w;
  }
  #pragma unroll
  for (int dy = -1; dy <= 1; dy++){
    const int h2 = hh + dy; if (h2 < 0 || h2 >= 20) continue;
    #pragma unroll
    for (int dx = -1; dx <= 1; dx++){
      const int w2 = ww + dx; if (w2 < 0 || w2 >= 15) continue;
      const bh8 vv = *(const bh8*)&e1[((size_t)b*300 + h2*15 + w2)*512 + c0];
      const int t = (dy+1)*3 + (dx+1);
      const bh8 wv = *(const bh8*)&dwt[t*512 + c0];
      #pragma unroll
      for (int j = 0; j < 8; j++)
        acc[j] += b2f((u16)vv[j]) * b2f((u16)wv[j]);
    }
  }
  bh8 ov;
  #pragma unroll
  for (int j = 0; j < 8; j++){
    float y = acc[j];
    y = (y >= 0.f) ? y : 0.01f*y;
    ov[j] = (short)f2b(y);
  }
  *(bh8*)&d1[((size_t)b*300 + sp)*512 + c0] = ov;
}

// ---------------- BN: one stats pass (5 sums, bf16 inputs), analytic finalize, final write ----------------
__global__ __launch_bounds__(256)
void stats_k(const u16* __restrict__ e3, const u16* __restrict__ res, float* __restrict__ st){
  const int tid = threadIdx.x;
  const int c0 = tid*2;
  const size_t r0 = (size_t)blockIdx.x * 64;
  float se0=0,se1=0,qe0=0,qe1=0,sr0=0,sr1=0,qr0=0,qr1=0,x0=0,x1=0;
  for (int rr = 0; rr < 64; rr++){
    const size_t o2 = (r0+rr)*512 + c0;
    const unsigned int eu = *(const unsigned int*)&e3[o2];
    const unsigned int ru = *(const unsigned int*)&res[o2];
    const float ex = b2f((u16)(eu & 0xffff)), ey = b2f((u16)(eu >> 16));
    const float rx = b2f((u16)(ru & 0xffff)), ry = b2f((u16)(ru >> 16));
    se0 += ex; se1 += ey; qe0 += ex*ex; qe1 += ey*ey;
    sr0 += rx; sr1 += ry; qr0 += rx*rx; qr1 += ry*ry;
    x0  += ex*rx; x1 += ey*ry;
  }
  atomicAdd(&st[c0], se0);      atomicAdd(&st[c0+1], se1);
  atomicAdd(&st[512+c0], qe0);  atomicAdd(&st[512+c0+1], qe1);
  atomicAdd(&st[1024+c0], sr0); atomicAdd(&st[1024+c0+1], sr1);
  atomicAdd(&st[1536+c0], qr0); atomicAdd(&st[1536+c0+1], qr1);
  atomicAdd(&st[2048+c0], x0);  atomicAdd(&st[2048+c0+1], x1);
}
__global__ void fin_k(float* st, const float* __restrict__ we, const float* __restrict__ be,
                      const float* __restrict__ wo, const float* __restrict__ bo){
  const int c = threadIdx.x;
  const float Nf = 19200.f, iN = 1.f/19200.f;
  const float Se = st[c], Qe = st[512+c], Sr = st[1024+c], Qr = st[1536+c], X = st[2048+c];
  const float me = Se*iN;
  const float ve = Qe*iN - me*me;
  const float ae = we[c]*rsqrtf(ve + 1e-5f);
  const float bev = be[c] - me*ae;
  const float So = Sr + ae*Se + Nf*bev;
  const float Qo = Qr + ae*ae*Qe + Nf*bev*bev + 2.f*ae*X + 2.f*bev*Sr + 2.f*ae*bev*Se;
  const float mo = So*iN;
  const float vo = Qo*iN - mo*mo;
  const float ao = wo[c]*rsqrtf(vo + 1e-5f);
  const float bov = bo[c] - mo*ao;
  st[2560+c] = ae; st[3072+c] = bev; st[3584+c] = ao; st[4096+c] = bov;
}
__global__ __launch_bounds__(256)
void final_kernel(const u16* __restrict__ res, const u16* __restrict__ e3,
                  const float* __restrict__ st, float* __restrict__ outp)
{
  __shared__ float tile[64][65];
  const int spt = blockIdx.x, cht = blockIdx.y, b = blockIdx.z;
  const int tid = threadIdx.x;
  const int sp0 = spt*64, ch0 = cht*64;
  for (int idx = tid; idx < 2048; idx += 256){
    const int cl = (idx & 31)*2, sl = idx >> 5;
    const int sp = sp0 + sl;
    float v0 = 0.f, v1 = 0.f;
    if (sp < 300){
      const size_t off = ((size_t)b*300 + sp)*512 + ch0 + cl;
      const int c = ch0 + cl;
      const unsigned int eu = *(const unsigned int*)&e3[off];
      const unsigned int ru = *(const unsigned int*)&res[off];
      const float e0 = b2f((u16)(eu & 0xffff))*st[2560+c]   + st[3072+c];
      const float e1 = b2f((u16)(eu >> 16))   *st[2560+c+1] + st[3072+c+1];
      v0 = (b2f((u16)(ru & 0xffff)) + e0)*st[3584+c]   + st[4096+c];
      v1 = (b2f((u16)(ru >> 16))    + e1)*st[3584+c+1] + st[4096+c+1];
    }
    tile[sl][cl] = v0; tile[sl][cl+1] = v1;
  }
  __syncthreads();
  for (int idx = tid; idx < 4096; idx += 256){
    const int sl = idx & 63, cl = idx >> 6;
    const int sp = sp0 + sl;
    if (sp < 300)
      outp[((size_t)b*512 + ch0 + cl)*300 + sp] = tile[sl][cl];
  }
}

// ---------------- host ----------------
extern "C" void kernel_launch(void* const* d_in, const int* in_sizes, int n_in,
                              void* d_out, int out_size, void* d_ws, size_t ws_size,
                              hipStream_t stream)
{
  const float* x1    = (const float*)d_in[0];
  const float* x2    = (const float*)d_in[1];
  const float* cp1_w = (const float*)d_in[2];
  const float* cp1_b = (const float*)d_in[3];
  const float* ln1_w = (const float*)d_in[4];
  const float* ln1_b = (const float*)d_in[5];
  const float* cp2_w = (const float*)d_in[6];
  const float* cp2_b = (const float*)d_in[7];
  const float* ln2_w = (const float*)d_in[8];
  const float* ln2_b = (const float*)d_in[9];
  const float* skv1w = (const float*)d_in[10];
  const float* skv2w = (const float*)d_in[11];
  const float* ckv1w = (const float*)d_in[12];
  const float* ckv2w = (const float*)d_in[13];
  const float* resw  = (const float*)d_in[14];
  const float* ce1w  = (const float*)d_in[15];
  const float* ce1b  = (const float*)d_in[16];
  const float* dww   = (const float*)d_in[17];
  const float* dwb   = (const float*)d_in[18];
  const float* ce3w  = (const float*)d_in[19];
  const float* ce3b  = (const float*)d_in[20];
  const float* bnew  = (const float*)d_in[21];
  const float* bneb  = (const float*)d_in[22];
  const float* bnow  = (const float*)d_in[23];
  const float* bnob  = (const float*)d_in[24];
  float* out = (float*)d_out;
  char* ws = (char*)d_ws;

  const size_t SZ_T    = (size_t)19200*512*2;
  const size_t SZ_APRE = (size_t)19200*1024*2;
  const size_t SZ_CKV  = (size_t)32768*640*2;
  const size_t SZ_CT   = (size_t)64*512*320*2;
  const size_t SZ_F32  = (size_t)19200*512*4;

  size_t off = 0;
  auto AL = [&](size_t sz){ size_t r = off; off += (sz + 255) & ~(size_t)255; return r; };
  const size_t oR0 = AL(2*SZ_T);
  const size_t oR1 = AL(2*SZ_CKV);
  const size_t oR2 = AL(2*SZ_T);
  const size_t oR3 = AL(2*SZ_CT + 4096);
  const size_t oR4 = AL(SZ_F32);
  const size_t oR5 = AL((size_t)2*64*8*64*64*2);
  const size_t oR6 = AL((size_t)2*64*4*80*96*2);
  const size_t oWcp1  = AL((size_t)1024*512*2);
  const size_t oWcp2  = AL((size_t)1024*512*2);
  const size_t oWskv1 = AL((size_t)1024*512*2);
  const size_t oWskv2 = AL((size_t)1024*512*2);
  const size_t oWckv1 = AL((size_t)640*320*2);
  const size_t oWckv2 = AL((size_t)640*320*2);
  const size_t oWresce = AL((size_t)1024*1024*2);
  const size_t oWce3  = AL((size_t)512*512*2);
  const size_t oWdw   = AL((size_t)9*512*2);
  const size_t oST    = AL(20480);
  (void)ws_size; (void)in_sizes; (void)n_in; (void)out_size;

  u16* t1    = (u16*)(ws + oR0);
  u16* merge = (u16*)(ws + oR0);
  u16* apre1 = (u16*)(ws + oR1);
  u16* ckv1  = (u16*)(ws + oR1);
  u16* s1    = (u16*)(ws + oR2);
  u16* s2    = (u16*)(ws + oR2 + SZ_T);
  u16* e1    = s1;
  u16* d1    = s2;
  u16* cT1   = (u16*)(ws + oR3);
  u16* cT2   = (u16*)(ws + oR3 + SZ_CT);
  u16* slack = (u16*)(ws + oR3 + 2*SZ_CT);
  u16* e3b   = (u16*)(ws + oR3);
  u16* resb  = (u16*)(ws + oR4);
  u16* csT   = (u16*)(ws + oR5);
  u16* ccT   = (u16*)(ws + oR6);
  u16* wcp1  = (u16*)(ws + oWcp1);
  u16* wcp2  = (u16*)(ws + oWcp2);
  u16* wskv1 = (u16*)(ws + oWskv1);
  u16* wskv2 = (u16*)(ws + oWskv2);
  u16* wckv1 = (u16*)(ws + oWckv1);
  u16* wckv2 = (u16*)(ws + oWckv2);
  u16* wresce = (u16*)(ws + oWresce);
  u16* wce3  = (u16*)(ws + oWce3);
  u16* wdw   = (u16*)(ws + oWdw);
  float* st  = (float*)(ws + oST);

  u16* kv1   = apre1;
  u16* ckv2  = ckv1 + (size_t)32768*640;

  hipMemsetAsync(st, 0, 10240, stream);
  pack_all<<<dim3(2048,10),256,0,stream>>>(cp1_w, cp2_w, skv1w, skv2w, resw, ce1w, ce3w, dww,
                                           ckv1w, ckv2w,
                                           wcp1, wcp2, wskv1, wskv2, wresce, wce3, wdw, slack,
                                           wckv1, wckv2);

  transpose_k<<<dim3(10,16,128),256,0,stream>>>(x1, x2, t1);

  // cp1+cp2 batched: 256x256 gemm2 (round-10 schedule, unclamped)
  gemm2<0,1><<<dim3(4,150),512,0,stream>>>(t1,512, wcp1,wcp2,512, 19200L,
                                           apre1,nullptr,1024, cp1_b,cp2_b, 512);

  ln_kernel<<<dim3(256,2,2),256,0,stream>>>(apre1, ln1_w, ln1_b, ln2_w, ln2_b, s1, cT1);

  gemm2<0,0><<<dim3(4,150),512,0,stream>>>(s1,512, wskv1,wskv2,512, 19200L,
                                           kv1,nullptr,1024, nullptr,nullptr, 512);

  ctx_kernel<64,64,64><<<dim3(8,64,2),256,0,stream>>>(kv1, kv1 + (size_t)19200*1024, csT, 300, 1024, 512, 0.125f);

  // ckv pair (N=640 -> keep 256x128 kernel)
  gemm_k<0,0><<<dim3(5,256),512,0,stream>>>(cT1,320, wckv1,wckv2,320, 32768L,
                                            ckv1,nullptr,640, nullptr,nullptr, 320);

  ctx_kernel<80,75,96><<<dim3(4,64,2),256,0,stream>>>(ckv1, ckv2, ccT, 512, 640, 320, 0.115470054f);

  spch_out_kernel<<<dim3(8,64,3),256,0,stream>>>(s1, s2, csT, cT1, cT2, ccT, merge);

  gemm2<2,0><<<dim3(4,75),512,0,stream>>>(merge,1024, wresce,nullptr,1024, (long)1<<40,
                                          e1, (float*)resb, 512, ce1b,nullptr, 1024);

  dw_kernel<<<4800,256,0,stream>>>(e1, wdw, dwb, d1);

  gemm2<0,1><<<dim3(2,75),512,0,stream>>>(d1,512, wce3,nullptr,512, (long)1<<40,
                                          e3b,nullptr,512, ce3b,nullptr, 512);

  stats_k<<<300,256,0,stream>>>(e3b, resb, st);
  fin_k<<<1,512,0,stream>>>(st, bnew, bneb, bnow, bnob);
  final_kernel<<<dim3(5,8,64),256,0,stream>>>(resb, e3b, st, out);
}

// Round 18
// 489.862 us; speedup vs baseline: 1.1449x; 1.1449x over previous
//
#include <hip/hip_runtime.h>

typedef unsigned short u16;
typedef __attribute__((ext_vector_type(8))) short bh8;
typedef __attribute__((ext_vector_type(4))) float f4;

__device__ __forceinline__ u16 f2b(float f){
  unsigned int u = __float_as_uint(f);
  u += 0x7fffu + ((u >> 16) & 1u);
  return (u16)(u >> 16);
}
__device__ __forceinline__ float b2f(u16 h){
  return __uint_as_float(((unsigned int)h) << 16);
}
__device__ __forceinline__ void gl16(const u16* g, u16* l){
  __builtin_amdgcn_global_load_lds((const __attribute__((address_space(1))) void*)g,
                                   (__attribute__((address_space(3))) void*)l, 16, 0, 0);
}

// ---------------- merged packing ----------------
__global__ void pack_all(const float* __restrict__ s0, const float* __restrict__ s1,
                         const float* __restrict__ s2, const float* __restrict__ s3,
                         const float* __restrict__ s4, const float* __restrict__ s5,
                         const float* __restrict__ sce3, const float* __restrict__ sdw,
                         u16* __restrict__ d0, u16* __restrict__ d1,
                         u16* __restrict__ d2, u16* __restrict__ d3,
                         u16* __restrict__ d45, u16* __restrict__ dce3,
                         u16* __restrict__ ddw, u16* __restrict__ slack)
{
  const int i = blockIdx.x*256 + threadIdx.x;
  const int y = blockIdx.y;
  if (y < 6){
    const float* src = (y==0)?s0:(y==1)?s1:(y==2)?s2:(y==3)?s3:(y==4)?s4:s5;
    u16* dst = (y==0)?d0:(y==1)?d1:(y==2)?d2:(y==3)?d3:(y==4)?d45:(d45+524288);
    dst[i] = f2b(src[i]);
  } else if (y == 6){
    if (i < 262144) dce3[i] = f2b(sce3[i]);
  } else {
    if (i < 4608){
      int t = i >> 9, c = i & 511;
      ddw[i] = f2b(sdw[c*9 + t]);
    } else if (i < 4608 + 2048){
      slack[i - 4608] = 0;
    }
  }
}
__global__ void pack_ckv_k(const float* __restrict__ srcA, const float* __restrict__ srcB,
                           u16* __restrict__ dstA, u16* __restrict__ dstB){
  int i = blockIdx.x*256 + threadIdx.x; // 640*320
  const float* src = blockIdx.y ? srcB : srcA;
  u16* dst = blockIdx.y ? dstB : dstA;
  int nn = i / 320, kk = i - (i/320)*320;
  int t_ = (nn >= 320) ? 1 : 0;
  int rem = nn - t_*320;
  int hh = rem / 80, dd = rem - hh*80;
  int kh = kk / 80, kd = kk - kh*80;
  float v = 0.f;
  if (dd < 75 && kd < 75)
    v = src[(size_t)(t_*300 + hh*75 + dd)*300 + (kh*75 + kd)];
  dst[i] = f2b(v);
}

// ---------------- x (B,C,H,W) f32 -> t (B,N,C) bf16; z>=64 -> second input ----------------
__global__ __launch_bounds__(256)
void transpose_k(const float* __restrict__ xa, const float* __restrict__ xb, u16* __restrict__ t)
{
  __shared__ float tile[32][33];
  const int n0 = blockIdx.x * 32, c0 = blockIdx.y * 32;
  const int z = blockIdx.z;
  const int b = z & 63;
  const float* x = (z >= 64) ? xb : xa;
  u16* to = t + (size_t)(z >= 64 ? 19200*512 : 0);
  const int ln = threadIdx.x & 31, lr = threadIdx.x >> 5;
  #pragma unroll
  for (int q = 0; q < 4; q++) {
    const int c = c0 + lr + q*8, n = n0 + ln;
    tile[lr + q*8][ln] = (n < 300) ? x[((long)b*512 + c)*300 + n] : 0.f;
  }
  __syncthreads();
  #pragma unroll
  for (int q = 0; q < 4; q++) {
    const int n = n0 + lr + q*8;
    if (n < 300) to[((long)b*300 + n)*512 + c0 + ln] = f2b(tile[ln][lr + q*8]);
  }
}

// ---------------- 256x128 MFMA GEMM (3-stage counted vmcnt) — proven ----------------
template<int OUTF, int HASB>
__global__ __launch_bounds__(512)
void gemm_k(const u16* __restrict__ A, int lda,
            const u16* __restrict__ Bw, const u16* __restrict__ Bw2, int ldb, long mhalf,
            u16* __restrict__ Cb, float* __restrict__ Cf, int ldc,
            const float* __restrict__ bias, const float* __restrict__ bias2, int K)
{
  __shared__ u16 As[3][8192];
  __shared__ u16 Bs[3][4096];
  const int tid = threadIdx.x;
  const int gx = gridDim.x;
  const int nwg = gx * gridDim.y;
  const int flat = blockIdx.y * gx + blockIdx.x;
  const int qq = nwg >> 3, rr = nwg & 7, xcd = flat & 7, lin = flat >> 3;
  const int newid = (xcd < rr ? xcd*(qq+1) : rr*(qq+1) + (xcd-rr)*qq) + lin;
  const long n0 = (long)(newid % gx) * 128;
  const long m0 = (long)(newid / gx) * 256;
  const u16* Bwp = Bw; const float* bp = bias;
  if (Bw2 != nullptr && m0 >= mhalf){ Bwp = Bw2; bp = bias2; }
  const int wave = tid >> 6, lane = tid & 63;
  const int l15 = lane & 15, lg = lane >> 4;
  const int wr = (wave >> 1) * 64, wc = (wave & 1) * 64;
  const int arow = tid >> 2;
  const int aseg = ((tid & 3) ^ ((arow >> 1) & 3)) * 8;
  const u16* Ag0 = A + (m0 + arow) * (long)lda + aseg;
  const u16* Ag1 = A + (m0 + 128 + arow) * (long)lda + aseg;
  const u16* Bg0 = Bwp + (n0 + arow) * (long)ldb + aseg;
  const int to8 = tid * 8;
  int roA[4], roB[4];
  #pragma unroll
  for (int i = 0; i < 4; i++){
    const int rA = wr + i*16 + l15;
    roA[i] = rA*32 + ((lg ^ ((rA >> 1) & 3)) * 8);
    const int rB = wc + i*16 + l15;
    roB[i] = rB*32 + ((lg ^ ((rB >> 1) & 3)) * 8);
  }
  f4 acc[4][4] = {};
  const int NT = K >> 5;
  {
    gl16(Ag0, &As[0][to8]); gl16(Ag1, &As[0][4096 + to8]); gl16(Bg0, &Bs[0][to8]);
    gl16(Ag0 + 32, &As[1][to8]); gl16(Ag1 + 32, &As[1][4096 + to8]); gl16(Bg0 + 32, &Bs[1][to8]);
  }
  int rd = 0;
  for (int t = 0; t < NT; t++) {
    if (t < NT - 1) { asm volatile("s_waitcnt vmcnt(3)" ::: "memory"); }
    else            { asm volatile("s_waitcnt vmcnt(0)" ::: "memory"); }
    __builtin_amdgcn_sched_barrier(0);
    __builtin_amdgcn_s_barrier();
    __builtin_amdgcn_sched_barrier(0);
    if (t + 2 < NT) {
      int wb = rd + 2; if (wb >= 3) wb -= 3;
      const int kt = (t + 2) << 5;
      gl16(Ag0 + kt, &As[wb][to8]); gl16(Ag1 + kt, &As[wb][4096 + to8]); gl16(Bg0 + kt, &Bs[wb][to8]);
    }
    bh8 af[4], bf[4];
    #pragma unroll
    for (int mi = 0; mi < 4; mi++) af[mi] = *(const bh8*)&As[rd][roA[mi]];
    #pragma unroll
    for (int ni = 0; ni < 4; ni++) bf[ni] = *(const bh8*)&Bs[rd][roB[ni]];
    __builtin_amdgcn_s_setprio(1);
    #pragma unroll
    for (int mi = 0; mi < 4; mi++)
      #pragma unroll
      for (int ni = 0; ni < 4; ni++)
        acc[mi][ni] = __builtin_amdgcn_mfma_f32_16x16x32_bf16(af[mi], bf[ni], acc[mi][ni], 0, 0, 0);
    __builtin_amdgcn_s_setprio(0);
    rd++; if (rd == 3) rd = 0;
  }
  if (OUTF == 2) {
    u16* resb16 = (u16*)Cf;
    if (n0 < 512) {
      #pragma unroll
      for (int ni = 0; ni < 4; ni++) {
        const long cn = n0 + wc + ni*16 + l15;
        #pragma unroll
        for (int mi = 0; mi < 4; mi++)
          #pragma unroll
          for (int r = 0; r < 4; r++) {
            const long cm = m0 + wr + mi*16 + lg*4 + r;
            resb16[cm * ldc + cn] = f2b(acc[mi][ni][r]);
          }
      }
    } else {
      #pragma unroll
      for (int ni = 0; ni < 4; ni++) {
        const long cn = n0 - 512 + wc + ni*16 + l15;
        const float bv = bias[cn];
        #pragma unroll
        for (int mi = 0; mi < 4; mi++)
          #pragma unroll
          for (int r = 0; r < 4; r++) {
            const long cm = m0 + wr + mi*16 + lg*4 + r;
            Cb[cm * ldc + cn] = f2b(acc[mi][ni][r] + bv);
          }
      }
    }
  } else {
    #pragma unroll
    for (int ni = 0; ni < 4; ni++) {
      const long cn = n0 + wc + ni*16 + l15;
      const float bv = HASB ? bp[cn] : 0.0f;
      #pragma unroll
      for (int mi = 0; mi < 4; mi++) {
        #pragma unroll
        for (int r = 0; r < 4; r++) {
          const long cm = m0 + wr + mi*16 + lg*4 + r;
          Cb[cm * ldc + cn] = f2b(acc[mi][ni][r] + bv);
        }
      }
    }
  }
}

// ---------------- LayerNorm(1024) + relu; split into s and cT; z selects stream ----------------
__global__ __launch_bounds__(256)
void ln_kernel(const u16* __restrict__ apre,
               const float* __restrict__ lw1, const float* __restrict__ lb1,
               const float* __restrict__ lw2, const float* __restrict__ lb2,
               u16* __restrict__ s, u16* __restrict__ cT)
{
  __shared__ u16 tile[40][520];
  const int bh = blockIdx.x;
  const int b = bh >> 2, h = bh & 3;
  const int z = blockIdx.y;
  const int p = blockIdx.z;
  const float* lw = p ? lw2 : lw1;
  const float* lb = p ? lb2 : lb1;
  const u16* ap = apre + (size_t)p * 19200 * 1024;
  u16* sp = s + (size_t)p * 19200 * 512;
  u16* cp = cT + (size_t)p * 64 * 512 * 320;
  const int dd0 = z ? 40 : 0;
  const int ndd = z ? 35 : 40;
  const int segbase = z ? 5 : 0;
  const int tid = threadIdx.x, w = tid >> 6, lane = tid & 63;
  const int r0 = b*300 + h*75 + dd0;
  for (int dl = w; dl < ndd; dl += 4){
    const int r = r0 + dl;
    const u16* row = ap + (size_t)r*1024 + lane*8;
    const bh8 vc = *(const bh8*)row;
    const bh8 vs = *(const bh8*)(row + 512);
    float fc[8], fs[8];
    float sm = 0.f, sq = 0.f;
    #pragma unroll
    for (int j = 0; j < 8; j++){
      fc[j] = b2f((u16)vc[j]); fs[j] = b2f((u16)vs[j]);
      sm += fc[j] + fs[j];
      sq += fc[j]*fc[j] + fs[j]*fs[j];
    }
    #pragma unroll
    for (int o = 32; o; o >>= 1){ sm += __shfl_xor(sm, o); sq += __shfl_xor(sq, o); }
    const float mean = sm * (1.f/1024.f);
    const float rstd = rsqrtf(sq*(1.f/1024.f) - mean*mean + 1e-5f);
    bh8 oc, os;
    #pragma unroll
    for (int j = 0; j < 8; j++){
      const int c = lane*8 + j;
      const float y1 = (fc[j]-mean)*rstd*lw[c] + lb[c];
      oc[j] = (short)f2b(fmaxf(y1, 0.f));
      const float y2 = (fs[j]-mean)*rstd*lw[512+c] + lb[512+c];
      os[j] = (short)f2b(fmaxf(y2, 0.f));
    }
    *(bh8*)&tile[dl][lane*8] = oc;
    *(bh8*)&sp[(size_t)r*512 + lane*8] = os;
  }
  __syncthreads();
  for (int i = tid; i < 2560; i += 256){
    const int c = i / 5, sg = i - (i/5)*5;
    const int seg = segbase + sg;
    bh8 ov;
    #pragma unroll
    for (int j = 0; j < 8; j++){
      const int dl = seg*8 + j - dd0;
      ov[j] = (short)((dl >= 0 && dl < ndd) ? tile[dl][c] : (u16)0);
    }
    *(bh8*)&cp[((size_t)b*512 + c)*320 + h*80 + seg*8] = ov;
  }
}

// ---------------- attn ctx ----------------
template<int D, int DREAL, int OS>
__global__ __launch_bounds__(256)
void ctx_kernel(const u16* __restrict__ kva, const u16* __restrict__ kvb,
                u16* __restrict__ outp, int K, int RS, int VOFF, float scale)
{
  constexpr int NT = D/16, MT = D/16, MTL = (MT+3)/4, SEG = D/8;
  __shared__ u16 vT[D][40];
  __shared__ u16 kT[D][40];
  const int h = blockIdx.x, b = blockIdx.y, iq = blockIdx.z;
  const int Hn = gridDim.x;
  const u16* base = (iq ? kvb : kva) + (size_t)b*K*RS + h*D;
  u16* out = outp + (((size_t)iq*64 + b)*Hn + h)*(size_t)(D*OS);
  const int tid = threadIdx.x, w = tid >> 6, lane = tid & 63, l15 = lane & 15, lg = lane >> 4;
  f4 acc[MTL][NT] = {};
  for (int k0 = 0; k0 < K; k0 += 32) {
    __syncthreads();
    for (int sI = tid; sI < 32*SEG; sI += 256) {
      const int nn = sI / SEG, dseg = sI - (sI/SEG)*SEG;
      bh8 kk = {}, vv = {};
      const int krow = k0 + nn;
      if (krow < K) {
        const u16* p = base + (size_t)krow*RS + dseg*8;
        kk = *(const bh8*)p;
        vv = *(const bh8*)(p + VOFF);
      }
      #pragma unroll
      for (int j = 0; j < 8; j++){
        kT[dseg*8+j][nn] = (u16)kk[j];
        vT[dseg*8+j][nn] = (u16)vv[j];
      }
    }
    __syncthreads();
    #pragma unroll
    for (int ii = 0; ii < MTL; ii++){
      const int mt = w + ii*4;
      if (MT % 4 != 0 && mt >= MT) break;
      const bh8 a = *(const bh8*)&vT[mt*16 + l15][lg*8];
      #pragma unroll
      for (int nt = 0; nt < NT; nt++){
        const bh8 bb = *(const bh8*)&kT[nt*16 + l15][lg*8];
        acc[ii][nt] = __builtin_amdgcn_mfma_f32_16x16x32_bf16(a, bb, acc[ii][nt], 0, 0, 0);
      }
    }
  }
  #pragma unroll
  for (int ii = 0; ii < MTL; ii++){
    const int mt = w + ii*4;
    if (MT % 4 != 0 && mt >= MT) continue;
    #pragma unroll
    for (int r = 0; r < 4; r++){
      const int e = mt*16 + lg*4 + r;
      float xs[NT]; float mx = -1e30f;
      #pragma unroll
      for (int nt = 0; nt < NT; nt++){
        float x = acc[ii][nt][r] * scale;
        if (DREAL != D && (nt*16 + l15) >= DREAL) x = -1e30f;
        xs[nt] = x; mx = fmaxf(mx, x);
      }
      mx = fmaxf(mx, __shfl_xor(mx,1)); mx = fmaxf(mx, __shfl_xor(mx,2));
      mx = fmaxf(mx, __shfl_xor(mx,4)); mx = fmaxf(mx, __shfl_xor(mx,8));
      float smv = 0.f;
      #pragma unroll
      for (int nt = 0; nt < NT; nt++){
        const float p = (xs[nt] > -1e29f) ? __expf(xs[nt]-mx) : 0.f;
        xs[nt] = p; smv += p;
      }
      smv += __shfl_xor(smv,1); smv += __shfl_xor(smv,2);
      smv += __shfl_xor(smv,4); smv += __shfl_xor(smv,8);
      const float inv = 1.f / smv;
      #pragma unroll
      for (int nt = 0; nt < NT; nt++)
        out[(size_t)e*OS + nt*16 + l15] = f2b(xs[nt]*inv);
      if (OS > D) out[(size_t)e*OS + D + l15] = 0;
    }
  }
}

// ---------------- merged spatial + channel out: z=0 -> spatial, z=1,2 -> channel ----------------
__global__ __launch_bounds__(256)
void spch_out_kernel(const u16* __restrict__ s1, const u16* __restrict__ s2,
                     const u16* __restrict__ csT,
                     const u16* __restrict__ cT1, const u16* __restrict__ cT2,
                     const u16* __restrict__ ccT, u16* __restrict__ merge)
{
  const int tid = threadIdx.x, w = tid >> 6, lane = tid & 63, l15 = lane & 15, lg = lane >> 4;
  const int b = blockIdx.y;
  if (blockIdx.z == 0) {
    const int h = blockIdx.x;
    const u16* c1 = csT + (((size_t)b)*8 + h)*4096;
    const u16* c2 = csT + (((size_t)64 + b)*8 + h)*4096;
    for (int mt = w; mt < 19; mt += 4) {
      const int m = mt*16 + l15;
      const bool mv = (m < 300);
      const u16* q1 = s1 + ((size_t)b*300 + m)*512 + h*64;
      const u16* q2 = s2 + ((size_t)b*300 + m)*512 + h*64;
      f4 acc[4] = {};
      #pragma unroll
      for (int kc = 0; kc < 2; kc++){
        bh8 a1 = {}, a2 = {};
        if (mv){ a1 = *(const bh8*)(q1 + kc*32 + lg*8); a2 = *(const bh8*)(q2 + kc*32 + lg*8); }
        #pragma unroll
        for (int nt = 0; nt < 4; nt++){
          const bh8 b2v = *(const bh8*)&c2[(size_t)(nt*16+l15)*64 + kc*32 + lg*8];
          acc[nt] = __builtin_amdgcn_mfma_f32_16x16x32_bf16(a1, b2v, acc[nt], 0, 0, 0);
          const bh8 b1v = *(const bh8*)&c1[(size_t)(nt*16+l15)*64 + kc*32 + lg*8];
          acc[nt] = __builtin_amdgcn_mfma_f32_16x16x32_bf16(a2, b1v, acc[nt], 0, 0, 0);
        }
      }
      #pragma unroll
      for (int nt = 0; nt < 4; nt++)
        #pragma unroll
        for (int r = 0; r < 4; r++){
          const int mm = mt*16 + lg*4 + r;
          if (mm < 300)
            merge[((size_t)b*300 + mm)*1024 + h*64 + nt*16 + l15] = f2b(acc[nt][r]);
        }
    }
  } else {
    const int idx = (blockIdx.z - 1)*8 + blockIdx.x;  // 0..15
    const int cb = idx >> 2, h = idx & 3;
    const int chbase = cb*128 + w*32;
    f4 acc[5][2] = {};
    #pragma unroll
    for (int oi = 0; oi < 2; oi++){
      const u16* Am = ccT + (((size_t)((oi==0)?1:0)*64 + b)*4 + h)*(size_t)(80*96);
      const u16* qb = (oi==0) ? cT1 : cT2;
      #pragma unroll
      for (int kc = 0; kc < 3; kc++){
        bh8 bf[2];
        #pragma unroll
        for (int nf = 0; nf < 2; nf++){
          const int ch = chbase + nf*16 + l15;
          bf[nf] = *(const bh8*)&qb[((size_t)b*512 + ch)*320 + h*80 + kc*32 + lg*8];
        }
        #pragma unroll
        for (int mt = 0; mt < 5; mt++){
          const bh8 a = *(const bh8*)&Am[(size_t)(mt*16+l15)*96 + kc*32 + lg*8];
          #pragma unroll
          for (int nf = 0; nf < 2; nf++)
            acc[mt][nf] = __builtin_amdgcn_mfma_f32_16x16x32_bf16(a, bf[nf], acc[mt][nf], 0, 0, 0);
        }
      }
    }
    #pragma unroll
    for (int mt = 0; mt < 5; mt++)
      #pragma unroll
      for (int nf = 0; nf < 2; nf++)
        #pragma unroll
        for (int r = 0; r < 4; r++){
          const int e = mt*16 + lg*4 + r;
          if (e < 75)
            merge[((size_t)b*300 + h*75 + e)*1024 + 512 + chbase + nf*16 + l15] = f2b(acc[mt][nf][r]);
        }
  }
}

// ---------------- depthwise 3x3 + bias + leaky(0.01) ----------------
__global__ __launch_bounds__(256)
void dw_kernel(const u16* __restrict__ e1, const u16* __restrict__ dwt,
               const float* __restrict__ bias, u16* __restrict__ d1)
{
  const int idx = blockIdx.x*256 + threadIdx.x;
  const int cg = idx & 63;
  const int sp = (idx >> 6) % 300;
  const int b  = idx / (64*300);
  const int c0 = cg*8;
  const int hh = sp / 15, ww = sp - hh*15;
  float acc[8];
  {
    const float4 b0 = *(const float4*)&bias[c0];
    const float4 b1 = *(const float4*)&bias[c0+4];
    acc[0]=b0.x; acc[1]=b0.y; acc[2]=b0.z; acc[3]=b0.w;
    acc[4]=b1.x; acc[5]=b1.y; acc[6]=b1.z; acc[7]=b1.w;
  }
  #pragma unroll
  for (int dy = -1; dy <= 1; dy++){
    const int h2 = hh + dy; if (h2 < 0 || h2 >= 20) continue;
    #pragma unroll
    for (int dx = -1; dx <= 1; dx++){
      const int w2 = ww + dx; if (w2 < 0 || w2 >= 15) continue;
      const bh8 vv = *(const bh8*)&e1[((size_t)b*300 + h2*15 + w2)*512 + c0];
      const int t = (dy+1)*3 + (dx+1);
      const bh8 wv = *(const bh8*)&dwt[t*512 + c0];
      #pragma unroll
      for (int j = 0; j < 8; j++)
        acc[j] += b2f((u16)vv[j]) * b2f((u16)wv[j]);
    }
  }
  bh8 ov;
  #pragma unroll
  for (int j = 0; j < 8; j++){
    float y = acc[j];
    y = (y >= 0.f) ? y : 0.01f*y;
    ov[j] = (short)f2b(y);
  }
  *(bh8*)&d1[((size_t)b*300 + sp)*512 + c0] = ov;
}

// ---------------- BN: one stats pass (5 sums, bf16 inputs), analytic finalize, final write ----------------
__global__ __launch_bounds__(256)
void stats_k(const u16* __restrict__ e3, const u16* __restrict__ res, float* __restrict__ st){
  const int tid = threadIdx.x;
  const int c0 = tid*2;
  const size_t r0 = (size_t)blockIdx.x * 64;
  float se0=0,se1=0,qe0=0,qe1=0,sr0=0,sr1=0,qr0=0,qr1=0,x0=0,x1=0;
  for (int rr = 0; rr < 64; rr++){
    const size_t o2 = (r0+rr)*512 + c0;
    const unsigned int eu = *(const unsigned int*)&e3[o2];
    const unsigned int ru = *(const unsigned int*)&res[o2];
    const float ex = b2f((u16)(eu & 0xffff)), ey = b2f((u16)(eu >> 16));
    const float rx = b2f((u16)(ru & 0xffff)), ry = b2f((u16)(ru >> 16));
    se0 += ex; se1 += ey; qe0 += ex*ex; qe1 += ey*ey;
    sr0 += rx; sr1 += ry; qr0 += rx*rx; qr1 += ry*ry;
    x0  += ex*rx; x1 += ey*ry;
  }
  atomicAdd(&st[c0], se0);      atomicAdd(&st[c0+1], se1);
  atomicAdd(&st[512+c0], qe0);  atomicAdd(&st[512+c0+1], qe1);
  atomicAdd(&st[1024+c0], sr0); atomicAdd(&st[1024+c0+1], sr1);
  atomicAdd(&st[1536+c0], qr0); atomicAdd(&st[1536+c0+1], qr1);
  atomicAdd(&st[2048+c0], x0);  atomicAdd(&st[2048+c0+1], x1);
}
__global__ void fin_k(float* st, const float* __restrict__ we, const float* __restrict__ be,
                      const float* __restrict__ wo, const float* __restrict__ bo){
  const int c = threadIdx.x;
  const float Nf = 19200.f, iN = 1.f/19200.f;
  const float Se = st[c], Qe = st[512+c], Sr = st[1024+c], Qr = st[1536+c], X = st[2048+c];
  const float me = Se*iN;
  const float ve = Qe*iN - me*me;
  const float ae = we[c]*rsqrtf(ve + 1e-5f);
  const float bev = be[c] - me*ae;
  const float So = Sr + ae*Se + Nf*bev;
  const float Qo = Qr + ae*ae*Qe + Nf*bev*bev + 2.f*ae*X + 2.f*bev*Sr + 2.f*ae*bev*Se;
  const float mo = So*iN;
  const float vo = Qo*iN - mo*mo;
  const float ao = wo[c]*rsqrtf(vo + 1e-5f);
  const float bov = bo[c] - mo*ao;
  st[2560+c] = ae; st[3072+c] = bev; st[3584+c] = ao; st[4096+c] = bov;
}
__global__ __launch_bounds__(256)
void final_kernel(const u16* __restrict__ res, const u16* __restrict__ e3,
                  const float* __restrict__ st, float* __restrict__ outp)
{
  __shared__ float tile[64][65];
  const int spt = blockIdx.x, cht = blockIdx.y, b = blockIdx.z;
  const int tid = threadIdx.x;
  const int sp0 = spt*64, ch0 = cht*64;
  for (int idx = tid; idx < 2048; idx += 256){
    const int cl = (idx & 31)*2, sl = idx >> 5;
    const int sp = sp0 + sl;
    float v0 = 0.f, v1 = 0.f;
    if (sp < 300){
      const size_t off = ((size_t)b*300 + sp)*512 + ch0 + cl;
      const int c = ch0 + cl;
      const unsigned int eu = *(const unsigned int*)&e3[off];
      const unsigned int ru = *(const unsigned int*)&res[off];
      const float e0 = b2f((u16)(eu & 0xffff))*st[2560+c]   + st[3072+c];
      const float e1 = b2f((u16)(eu >> 16))   *st[2560+c+1] + st[3072+c+1];
      v0 = (b2f((u16)(ru & 0xffff)) + e0)*st[3584+c]   + st[4096+c];
      v1 = (b2f((u16)(ru >> 16))    + e1)*st[3584+c+1] + st[4096+c+1];
    }
    tile[sl][cl] = v0; tile[sl][cl+1] = v1;
  }
  __syncthreads();
  for (int idx = tid; idx < 4096; idx += 256){
    const int sl = idx & 63, cl = idx >> 6;
    const int sp = sp0 + sl;
    if (sp < 300)
      outp[((size_t)b*512 + ch0 + cl)*300 + sp] = tile[sl][cl];
  }
}

// ---------------- host ----------------
extern "C" void kernel_launch(void* const* d_in, const int* in_sizes, int n_in,
                              void* d_out, int out_size, void* d_ws, size_t ws_size,
                              hipStream_t stream)
{
  const float* x1    = (const float*)d_in[0];
  const float* x2    = (const float*)d_in[1];
  const float* cp1_w = (const float*)d_in[2];
  const float* cp1_b = (const float*)d_in[3];
  const float* ln1_w = (const float*)d_in[4];
  const float* ln1_b = (const float*)d_in[5];
  const float* cp2_w = (const float*)d_in[6];
  const float* cp2_b = (const float*)d_in[7];
  const float* ln2_w = (const float*)d_in[8];
  const float* ln2_b = (const float*)d_in[9];
  const float* skv1w = (const float*)d_in[10];
  const float* skv2w = (const float*)d_in[11];
  const float* ckv1w = (const float*)d_in[12];
  const float* ckv2w = (const float*)d_in[13];
  const float* resw  = (const float*)d_in[14];
  const float* ce1w  = (const float*)d_in[15];
  const float* ce1b  = (const float*)d_in[16];
  const float* dww   = (const float*)d_in[17];
  const float* dwb   = (const float*)d_in[18];
  const float* ce3w  = (const float*)d_in[19];
  const float* ce3b  = (const float*)d_in[20];
  const float* bnew  = (const float*)d_in[21];
  const float* bneb  = (const float*)d_in[22];
  const float* bnow  = (const float*)d_in[23];
  const float* bnob  = (const float*)d_in[24];
  float* out = (float*)d_out;
  char* ws = (char*)d_ws;

  const size_t SZ_T    = (size_t)19200*512*2;
  const size_t SZ_APRE = (size_t)19200*1024*2;
  const size_t SZ_CKV  = (size_t)32768*640*2;
  const size_t SZ_CT   = (size_t)64*512*320*2;
  const size_t SZ_F32  = (size_t)19200*512*4;

  size_t off = 0;
  auto AL = [&](size_t sz){ size_t r = off; off += (sz + 255) & ~(size_t)255; return r; };
  const size_t oR0 = AL(2*SZ_T);
  const size_t oR1 = AL(2*SZ_CKV);
  const size_t oR2 = AL(2*SZ_T);
  const size_t oR3 = AL(2*SZ_CT + 4096);
  const size_t oR4 = AL(SZ_F32);
  const size_t oR5 = AL((size_t)2*64*8*64*64*2);
  const size_t oR6 = AL((size_t)2*64*4*80*96*2);
  const size_t oWcp1  = AL((size_t)1024*512*2);
  const size_t oWcp2  = AL((size_t)1024*512*2);
  const size_t oWskv1 = AL((size_t)1024*512*2);
  const size_t oWskv2 = AL((size_t)1024*512*2);
  const size_t oWckv1 = AL((size_t)640*320*2);
  const size_t oWckv2 = AL((size_t)640*320*2);
  const size_t oWresce = AL((size_t)1024*1024*2);
  const size_t oWce3  = AL((size_t)512*512*2);
  const size_t oWdw   = AL((size_t)9*512*2);
  const size_t oST    = AL(20480);
  (void)ws_size; (void)in_sizes; (void)n_in; (void)out_size;

  u16* t1    = (u16*)(ws + oR0);
  u16* merge = (u16*)(ws + oR0);
  u16* apre1 = (u16*)(ws + oR1);
  u16* ckv1  = (u16*)(ws + oR1);
  u16* s1    = (u16*)(ws + oR2);
  u16* s2    = (u16*)(ws + oR2 + SZ_T);
  u16* e1    = s1;
  u16* d1    = s2;
  u16* cT1   = (u16*)(ws + oR3);
  u16* cT2   = (u16*)(ws + oR3 + SZ_CT);
  u16* slack = (u16*)(ws + oR3 + 2*SZ_CT);
  u16* e3b   = (u16*)(ws + oR3);
  u16* resb  = (u16*)(ws + oR4);
  u16* csT   = (u16*)(ws + oR5);
  u16* ccT   = (u16*)(ws + oR6);
  u16* wcp1  = (u16*)(ws + oWcp1);
  u16* wcp2  = (u16*)(ws + oWcp2);
  u16* wskv1 = (u16*)(ws + oWskv1);
  u16* wskv2 = (u16*)(ws + oWskv2);
  u16* wckv1 = (u16*)(ws + oWckv1);
  u16* wckv2 = (u16*)(ws + oWckv2);
  u16* wresce = (u16*)(ws + oWresce);
  u16* wce3  = (u16*)(ws + oWce3);
  u16* wdw   = (u16*)(ws + oWdw);
  float* st  = (float*)(ws + oST);

  u16* kv1   = apre1;
  u16* ckv2  = ckv1 + (size_t)32768*640;

  hipMemsetAsync(st, 0, 10240, stream);
  pack_all<<<dim3(2048,8),256,0,stream>>>(cp1_w, cp2_w, skv1w, skv2w, resw, ce1w, ce3w, dww,
                                          wcp1, wcp2, wskv1, wskv2, wresce, wce3, wdw, slack);
  pack_ckv_k<<<dim3(800,2),256,0,stream>>>(ckv1w, ckv2w, wckv1, wckv2);

  transpose_k<<<dim3(10,16,128),256,0,stream>>>(x1, x2, t1);

  gemm_k<0,1><<<dim3(8,150),512,0,stream>>>(t1,512, wcp1,wcp2,512, 19200L,
                                            apre1,nullptr,1024, cp1_b,cp2_b, 512);

  ln_kernel<<<dim3(256,2,2),256,0,stream>>>(apre1, ln1_w, ln1_b, ln2_w, ln2_b, s1, cT1);

  gemm_k<0,0><<<dim3(8,150),512,0,stream>>>(s1,512, wskv1,wskv2,512, 19200L,
                                            kv1,nullptr,1024, nullptr,nullptr, 512);

  ctx_kernel<64,64,64><<<dim3(8,64,2),256,0,stream>>>(kv1, kv1 + (size_t)19200*1024, csT, 300, 1024, 512, 0.125f);

  gemm_k<0,0><<<dim3(5,256),512,0,stream>>>(cT1,320, wckv1,wckv2,320, 32768L,
                                            ckv1,nullptr,640, nullptr,nullptr, 320);

  ctx_kernel<80,75,96><<<dim3(4,64,2),256,0,stream>>>(ckv1, ckv2, ccT, 512, 640, 320, 0.115470054f);

  spch_out_kernel<<<dim3(8,64,3),256,0,stream>>>(s1, s2, csT, cT1, cT2, ccT, merge);

  gemm_k<2,0><<<dim3(8,75),512,0,stream>>>(merge,1024, wresce,nullptr,1024, (long)1<<40,
                                           e1, (float*)resb, 512, ce1b,nullptr, 1024);

  dw_kernel<<<4800,256,0,stream>>>(e1, wdw, dwb, d1);

  gemm_k<0,1><<<dim3(4,75),512,0,stream>>>(d1,512, wce3,nullptr,512, (long)1<<40,
                                           e3b,nullptr,512, ce3b,nullptr, 512);

  stats_k<<<300,256,0,stream>>>(e3b, resb, st);
  fin_k<<<1,512,0,stream>>>(st, bnew, bneb, bnow, bnob);
  final_kernel<<<dim3(5,8,64),256,0,stream>>>(resb, e3b, st, out);
}